// Round 1
// 232.869 us; speedup vs baseline: 1.0133x; 1.0133x over previous
//
#include <hip/hip_runtime.h>

// ============================================================================
// ROUND 13: attn_split rewritten with swapped QK^T (T12-style in-register P).
//  - s_T[t] = mfma(K, Q): lane holds P[n=l15][m=t*16+lg*4+r] (32 lane-local).
//  - PV k-dim uses custom m-order m(ks2,lg,j)=(2ks2+(j>>2))*16+lg*4+(j&3) so
//    the P A-frag is built IN REGISTERS (cvt_pk_bf16 pairs) -> no ldsP, no
//    bank conflicts, no f2bf chains. V columns permuted to match at the
//    qkv_gemm V-store (bit-twiddle within each 32-col group).
//  - mask: one uint4 per lane (row n=l15) instead of mk[4]+mkn[4] (saves 24 VGPR).
//  - ones-operand in registers; Q staged via ldsK. LDS 68.6KB -> 32KB.
// prep / combine / o_gemm unchanged; qkv_gemm only changes the V store index.
// ============================================================================

typedef __attribute__((ext_vector_type(8))) short short8;
typedef __attribute__((ext_vector_type(4))) short short4v;
typedef __attribute__((ext_vector_type(4))) float f32x4;
typedef __attribute__((ext_vector_type(4))) int int4v;

#define SCL2E 0.18033688011112042592f /* (1/8) * log2(e) */

__device__ __forceinline__ float bf2f(short s) {
  unsigned u = ((unsigned)(unsigned short)s) << 16;
  return __uint_as_float(u);
}
__device__ __forceinline__ short f2bf(float f) {
  unsigned u = __float_as_uint(f);
  u += 0x7fffu + ((u >> 16) & 1u);
  return (short)(u >> 16);
}
__device__ __forceinline__ int cvt_pk_bf16(float a, float b) {
  int r;
  asm("v_cvt_pk_bf16_f32 %0, %1, %2" : "=v"(r) : "v"(a), "v"(b));
  return r;
}
__device__ __forceinline__ void gld_lds16(const void* gp, void* lp) {
  __builtin_amdgcn_global_load_lds(
      (const __attribute__((address_space(1))) unsigned int*)gp,
      (__attribute__((address_space(3))) unsigned int*)lp, 16, 0, 0);
}
__device__ __forceinline__ short4v cvt4(float4 v) {
  short4v o;
  o[0] = f2bf(v.x); o[1] = f2bf(v.y); o[2] = f2bf(v.z); o[3] = f2bf(v.w);
  return o;
}
// Tiled layouts: element (row,k) -> frag-set-ordered offset (shorts).
__device__ __forceinline__ size_t off128(int row, int k) {
  return ((size_t)(((row >> 7) * 32 + (k >> 5)) * 8 + ((row >> 4) & 7)) << 9) +
         (((((k >> 3) & 3) * 16 + (row & 15)) << 3) + (k & 7));
}
__device__ __forceinline__ size_t off64(int row, int k) {
  return ((size_t)(((row >> 6) * 32 + (k >> 5)) * 4 + ((row >> 4) & 3)) << 9) +
         (((((k >> 3) & 3) * 16 + (row & 15)) << 3) + (k & 7));
}

// ---------------------------------------------------------------------------
// prep (unchanged): mask bit-pack + fp32->bf16 tiled conversion.
// ---------------------------------------------------------------------------
__global__ __launch_bounds__(256) void prep(
    const unsigned char* __restrict__ mask, unsigned long long* __restrict__ pm,
    const float* __restrict__ Wq, const float* __restrict__ Wkv,
    const float* __restrict__ Wo, const float* __restrict__ x,
    const float* __restrict__ ctx, short* __restrict__ wqb,
    short* __restrict__ wkvb, short* __restrict__ wob,
    short* __restrict__ xb, short* __restrict__ ctxb) {
  const int row = blockIdx.x;
  const int wave = threadIdx.x >> 6, lane = threadIdx.x & 63;
  const unsigned char p8 = mask[lane * 4 + 1];
  const int p32 = ((const int*)mask)[lane * 2 + 1];
  const int shift =
      (__ballot(p8 != 0) != 0ull) ? 0 : ((__ballot(p32 != 0) != 0ull) ? 2 : 3);
  const size_t mbase = ((size_t)row * 2048) << shift;
#pragma unroll
  for (int j = 0; j < 8; j++) {
    const int c = wave * 512 + j * 64 + lane;
    const unsigned long long bits = __ballot(mask[mbase + ((size_t)c << shift)] != 0);
    if (lane == 0) pm[(size_t)row * 32 + wave * 8 + j] = bits;
  }
  const int gid = blockIdx.x * 256 + threadIdx.x;  // [0, 524288)
  {  // x: 524288 float4
    const int e = gid * 4, r = e >> 10, k = e & 1023;
    *(short4v*)(xb + off128(r, k)) = cvt4(((const float4*)x)[gid]);
  }
  {  // ctx: 1048576 float4 -> 2 per thread
    int e = gid * 4, r = e >> 10, k = e & 1023;
    *(short4v*)(ctxb + off128(r, k)) = cvt4(((const float4*)ctx)[gid]);
    e = (gid + 524288) * 4; r = e >> 10; k = e & 1023;
    *(short4v*)(ctxb + off128(r, k)) = cvt4(((const float4*)ctx)[gid + 524288]);
  }
  {  // Wkv: 524288 float4
    const int e = gid * 4, r = e >> 10, k = e & 1023;
    *(short4v*)(wkvb + off128(r, k)) = cvt4(((const float4*)Wkv)[gid]);
  }
  if (gid < 262144) {  // Wq (128-tile), Wo (64-tile)
    const int e = gid * 4, r = e >> 10, k = e & 1023;
    *(short4v*)(wqb + off128(r, k)) = cvt4(((const float4*)Wq)[gid]);
    *(short4v*)(wob + off64(r, k)) = cvt4(((const float4*)Wo)[gid]);
  }
}

// ---------------------------------------------------------------------------
// qkv_gemm: identical GEMM; V epilogue stores into PERMUTED columns so that
// attn_split's natural lane order m(ks2,lg,j)=(2ks2+(j>>2))*16+lg*4+(j&3)
// reads contiguously. Permutation is within each 32-col group:
//   c(m) = (m&~31) | (((m>>2)&3)<<3) | (((m>>4)&1)<<2) | (m&3)
// ---------------------------------------------------------------------------
__global__ __launch_bounds__(256, 2)
void qkv_gemm(const short* __restrict__ xb, const short* __restrict__ ctxb,
              const short* __restrict__ wqb, const short* __restrict__ wkvb,
              const float* __restrict__ bias, short* __restrict__ qws,
              short* __restrict__ kws, short* __restrict__ vtws) {
  __shared__ __align__(16) short ldsA[8 * 512];
  __shared__ __align__(16) short ldsB[8 * 512];
  const int tid = threadIdx.x;
  const int wave = tid >> 6, lane = tid & 63;
  const int l15 = lane & 15, lg = lane >> 4;
  const int bx = blockIdx.x;
  const bool isKV = bx < 512;
  const int rt = isKV ? (bx >> 4) : ((bx - 512) >> 3);
  const int ct = isKV ? (bx & 15) : ((bx - 512) & 7);
  const short* Amat = isKV ? ctxb : xb;
  const short* Bw = isKV ? wkvb : wqb;
  const int wr = wave >> 1, wc = wave & 1;

  f32x4 acc[4][4];
#pragma unroll
  for (int i = 0; i < 4; i++)
#pragma unroll
    for (int j = 0; j < 4; j++) acc[i][j] = (f32x4){0.f, 0.f, 0.f, 0.f};

  const short* ga0 = Amat + (size_t)rt * 131072 + wave * 512 + lane * 8;
  const short* ga1 = ga0 + 2048;
  const short* gb0 = Bw + (size_t)ct * 131072 + wave * 512 + lane * 8;
  const short* gb1 = gb0 + 2048;
  short* la0 = &ldsA[wave * 512];
  short* la1 = &ldsA[(wave + 4) * 512];
  short* lb0 = &ldsB[wave * 512];
  short* lb1 = &ldsB[(wave + 4) * 512];

  for (int k0 = 0; k0 < 1024; k0 += 32) {
    const size_t koff = (size_t)(k0 >> 5) * 4096;
    __syncthreads();
    gld_lds16(ga0 + koff, la0);
    gld_lds16(ga1 + koff, la1);
    gld_lds16(gb0 + koff, lb0);
    gld_lds16(gb1 + koff, lb1);
    __syncthreads();
    short8 af[4], bfr[4];
#pragma unroll
    for (int t = 0; t < 4; t++)
      af[t] = *(const short8*)&ldsA[((wr * 4 + t) * 64 + lane) * 8];
#pragma unroll
    for (int t = 0; t < 4; t++)
      bfr[t] = *(const short8*)&ldsB[((wc * 4 + t) * 64 + lane) * 8];
#pragma unroll
    for (int i = 0; i < 4; i++)
#pragma unroll
      for (int j = 0; j < 4; j++)
        acc[i][j] =
            __builtin_amdgcn_mfma_f32_16x16x32_bf16(af[i], bfr[j], acc[i][j], 0, 0, 0);
  }

#pragma unroll
  for (int i = 0; i < 4; i++)
#pragma unroll
    for (int j = 0; j < 4; j++)
#pragma unroll
      for (int r = 0; r < 4; r++) {
        const int gr = rt * 128 + wr * 64 + i * 16 + lg * 4 + r;
        const int gc = ct * 128 + wc * 64 + j * 16 + l15;
        float v = acc[i][j][r];
        if (isKV) {
          v += bias[gc];
          const int b = gr >> 11, m = gr & 2047;
          const int kv = gc >> 10, hh = (gc >> 6) & 15, d = gc & 63;
          if (kv == 0)
            kws[((((size_t)b * 16 + hh) * 2048 + m) << 6) + d] = f2bf(v);
          else {
            // permuted V^T column so attn's in-register P-frag order matches
            const int mp = (m & ~31) | (((m >> 2) & 3) << 3) |
                           (((m >> 4) & 1) << 2) | (m & 3);
            vtws[(((size_t)b * 16 + hh) * 64 + d) * 2048 + mp] = f2bf(v);
          }
        } else {
          const int b = gr >> 10, n = gr & 1023, hh = gc >> 6, d = gc & 63;
          qws[((((size_t)b * 16 + hh) * 1024 + n) << 6) + d] = f2bf(v * SCL2E);
        }
      }
}

// ---------------------------------------------------------------------------
// attn_split (R13): swapped QK^T, in-register P, no ldsP. 512 blocks x 512
// threads, split-K x2, no-max exp2 softmax, l via ones-MFMA.
// LDS = ldsK(16KB) + ldsV(16KB) = 32KB.
// ---------------------------------------------------------------------------
__global__ __launch_bounds__(512, 6)
void attn_split(const short* __restrict__ Qg, const short* __restrict__ Kg,
                const short* __restrict__ Vtg,
                const unsigned int* __restrict__ pm,
                float* __restrict__ opart, float* __restrict__ lpart) {
  __shared__ __align__(16) short ldsK[8192];
  __shared__ __align__(16) short ldsV[8192];
  const int tid = threadIdx.x;
  const int w = tid >> 6, lane = tid & 63;
  const int l15 = lane & 15, lg = lane >> 4;
  const int bx = blockIdx.x;
  const int bhid = bx & 31, qt = (bx >> 5) & 7, half = bx >> 8;
  const int b = bhid >> 4, h = bhid & 15;
  const int n0 = qt * 128, m_base = half * 1024;
  const size_t bh = (size_t)b * 16 + h;
  const short* Qb = Qg + (bh * 1024 + n0) * 64;
  const short* Kb = Kg + (bh << 17);
  const short* Vb = Vtg + (bh << 17);
  // mask words for row n = l15 (same addr across lg -> broadcast)
  const unsigned int* pmw =
      pm + ((size_t)(b * 1024 + n0 + w * 16 + l15) << 6) + (m_base >> 5);

  // Stage Q through ldsK (exactly 16KB), pull frags, then ldsK is K's buffer.
#pragma unroll
  for (int ii = 0; ii < 2; ii++)
    gld_lds16(Qb + (size_t)(w * 16 + l15) * 64 + ii * 32 + lg * 8,
              &ldsK[(w * 2 + ii) * 512]);
  __syncthreads();
  short8 qf[2];
#pragma unroll
  for (int ks = 0; ks < 2; ks++)
    qf[ks] = *(const short8*)&ldsK[((w * 2 + ks) * 64 + lane) * 8];

  short8 onesf;
#pragma unroll
  for (int i = 0; i < 8; i++) onesf[i] = (short)0x3F80;  // bf16 1.0

  f32x4 o[4], lacc;
#pragma unroll
  for (int ct = 0; ct < 4; ct++) o[ct] = (f32x4){0.f, 0.f, 0.f, 0.f};
  lacc = (f32x4){0.f, 0.f, 0.f, 0.f};
  const int sb = lg * 4;

  for (int c = 0; c < 8; c++) {
    const int m0 = m_base + c * 128;
    const uint4 mk = *(const uint4*)(pmw + c * 4);
    __syncthreads();
#pragma unroll
    for (int ii = 0; ii < 2; ii++) {
      const int f = w * 2 + ii;
      const int t = f >> 1, ks = f & 1;
      gld_lds16(Kb + (size_t)(m0 + t * 16 + l15) * 64 + ks * 32 + lg * 8,
                &ldsK[f * 512]);
      const int vt = f >> 2, vk = f & 3;
      gld_lds16(Vb + (size_t)(vt * 16 + l15) * 2048 + (m0 + vk * 32 + lg * 8),
                &ldsV[f * 512]);
    }
    __syncthreads();

    // S^T = K * Q^T: lane holds S[n=l15][m = m0 + t*16 + lg*4 + r]
    int4v pw4[4];
#pragma unroll
    for (int h2 = 0; h2 < 2; h2++) {
      f32x4 s[4];
#pragma unroll
      for (int t2 = 0; t2 < 4; t2++) s[t2] = (f32x4){0.f, 0.f, 0.f, 0.f};
#pragma unroll
      for (int t2 = 0; t2 < 4; t2++) {
        const int t = h2 * 4 + t2;
#pragma unroll
        for (int ks = 0; ks < 2; ks++) {
          const short8 kf = *(const short8*)&ldsK[((t * 2 + ks) * 64 + lane) * 8];
          s[t2] = __builtin_amdgcn_mfma_f32_16x16x32_bf16(kf, qf[ks], s[t2], 0, 0, 0);
        }
      }
#pragma unroll
      for (int t2 = 0; t2 < 4; t2++) {
        const int t = h2 * 4 + t2;
        const unsigned int mw = ((t >> 1) == 0) ? mk.x
                              : ((t >> 1) == 1) ? mk.y
                              : ((t >> 1) == 2) ? mk.z : mk.w;
        float p[4];
#pragma unroll
        for (int r = 0; r < 4; r++) {
          const bool att = (mw >> (((t & 1) << 4) + sb + r)) & 1;
          p[r] = exp2f(att ? s[t2][r] : -1e30f);
        }
        // A-frag words: slice ks2 = t>>1, word pos = (t&1)*2 + {0,1}
        pw4[t >> 1][(t & 1) * 2] = cvt_pk_bf16(p[0], p[1]);
        pw4[t >> 1][(t & 1) * 2 + 1] = cvt_pk_bf16(p[2], p[3]);
      }
    }

    // PV: P A-frags are lane-local; V staged in matching permuted m-order.
#pragma unroll
    for (int ks2 = 0; ks2 < 4; ks2++) {
      const short8 pf = __builtin_bit_cast(short8, pw4[ks2]);
#pragma unroll
      for (int ct = 0; ct < 4; ct++) {
        const short8 vf = *(const short8*)&ldsV[((ct * 4 + ks2) * 64 + lane) * 8];
        o[ct] = __builtin_amdgcn_mfma_f32_16x16x32_bf16(pf, vf, o[ct], 0, 0, 0);
      }
      lacc = __builtin_amdgcn_mfma_f32_16x16x32_bf16(pf, onesf, lacc, 0, 0, 0);
    }
  }

#pragma unroll
  for (int ct = 0; ct < 4; ct++)
#pragma unroll
    for (int r = 0; r < 4; r++) {
      const int n = n0 + w * 16 + lg * 4 + r;
      opart[((size_t)half << 21) + (((size_t)b * 1024 + n) << 10) + h * 64 +
            ct * 16 + l15] = o[ct][r];
    }
  if (l15 == 0) {
#pragma unroll
    for (int r = 0; r < 4; r++) {
      const int n = n0 + w * 16 + lg * 4 + r;
      lpart[((size_t)half << 15) + bh * 1024 + n] = lacc[r];
    }
  }
}

// ---------------------------------------------------------------------------
// combine (unchanged): AO = (o0+o1)/(l0+l1), bf16, 64-TILED layout.
// ---------------------------------------------------------------------------
__global__ __launch_bounds__(256) void combine(
    const float* __restrict__ opart, const float* __restrict__ lpart,
    short* __restrict__ aoT) {
  const int gid = blockIdx.x * 256 + threadIdx.x;
  const size_t base = (size_t)gid * 4;
  const int row = (int)(base >> 10), col = (int)(base & 1023);
  const int b = row >> 10, n = row & 1023, h = col >> 6;
  const float4 o1 = *(const float4*)(opart + base);
  const float4 o2 = *(const float4*)(opart + (1u << 21) + base);
  const float l1 = lpart[(size_t)(b * 16 + h) * 1024 + n];
  const float l2 = lpart[(1u << 15) + (size_t)(b * 16 + h) * 1024 + n];
  const float inv = 1.f / fmaxf(l1 + l2, 1e-30f);
  short4v o;
  o[0] = f2bf((o1.x + o2.x) * inv); o[1] = f2bf((o1.y + o2.y) * inv);
  o[2] = f2bf((o1.z + o2.z) * inv); o[3] = f2bf((o1.w + o2.w) * inv);
  *(short4v*)(aoT + off64(row, col)) = o;
}

// ---------------------------------------------------------------------------
// o_gemm (unchanged): 64x64 tiles, 512 blocks, 8KB LDS.
// ---------------------------------------------------------------------------
__global__ __launch_bounds__(256, 2)
void o_gemm(const short* __restrict__ aoT, const short* __restrict__ wobT,
            float* __restrict__ Of) {
  __shared__ __align__(16) short ldsA[4 * 512];
  __shared__ __align__(16) short ldsB[4 * 512];
  const int tid = threadIdx.x;
  const int w = tid >> 6, lane = tid & 63;
  const int l15 = lane & 15, lg = lane >> 4;
  const int bx = blockIdx.x;
  const int rt = bx >> 4, ct = bx & 15;

  f32x4 acc[4];
#pragma unroll
  for (int j = 0; j < 4; j++) acc[j] = (f32x4){0.f, 0.f, 0.f, 0.f};

  const short* ga = aoT + (size_t)rt * 65536 + w * 512 + lane * 8;
  const short* gb = wobT + (size_t)ct * 65536 + w * 512 + lane * 8;
  short* la = &ldsA[w * 512];
  short* lb = &ldsB[w * 512];

  for (int k0 = 0; k0 < 1024; k0 += 32) {
    const size_t koff = (size_t)(k0 >> 5) * 2048;
    __syncthreads();
    gld_lds16(ga + koff, la);
    gld_lds16(gb + koff, lb);
    __syncthreads();
    const short8 af = *(const short8*)&ldsA[(w * 64 + lane) * 8];
#pragma unroll
    for (int j = 0; j < 4; j++) {
      const short8 bf = *(const short8*)&ldsB[(j * 64 + lane) * 8];
      acc[j] = __builtin_amdgcn_mfma_f32_16x16x32_bf16(af, bf, acc[j], 0, 0, 0);
    }
  }

#pragma unroll
  for (int j = 0; j < 4; j++)
#pragma unroll
    for (int r = 0; r < 4; r++) {
      const int gr = rt * 64 + w * 16 + lg * 4 + r;
      const int gc = ct * 64 + j * 16 + l15;
      Of[(size_t)gr * 1024 + gc] = acc[j][r];
    }
}

extern "C" void kernel_launch(void* const* d_in, const int* in_sizes, int n_in,
                              void* d_out, int out_size, void* d_ws, size_t ws_size,
                              hipStream_t stream) {
  const float* x   = (const float*)d_in[0];   // fp32 (2,1024,1024)
  const float* ctx = (const float*)d_in[1];   // fp32 (2,2048,1024)
  const unsigned char* mask = (const unsigned char*)d_in[2];  // (2,1024,2048)
  const float* Wq  = (const float*)d_in[3];
  const float* Wkv = (const float*)d_in[4];
  const float* bkv = (const float*)d_in[5];
  const float* Wo  = (const float*)d_in[6];
  float* out = (float*)d_out;                 // FP32 (2,1024,1024)

  char* wsb = (char*)d_ws;
  short* qws  = (short*)(wsb);                        // bf16 Q*scl  4MB @0
  short* kws  = (short*)(wsb + (4u << 20));           // bf16 K      8MB @4M
  short* vtws = (short*)(wsb + (12u << 20));          // bf16 V^T    8MB @12M
  short* wqb  = (short*)(wsb + (20u << 20));          // bf16 Wq(T)  2MB @20M
  short* wkvb = (short*)(wsb + (22u << 20));          // bf16 Wkv(T) 4MB @22M
  short* wob  = (short*)(wsb + (26u << 20));          // bf16 Wo(T)  2MB @26M
  unsigned long long* pmws = (unsigned long long*)(wsb + (28u << 20));  // .5MB
  float* opart = (float*)(wsb + (29u << 20));         // fp32 2x8MB  16MB @29M
  float* lpart = (float*)(wsb + (45u << 20));         // fp32 .25MB  @45M
  short* xb   = (short*)(wsb + (29u << 20));          // bf16 x(T)   4MB @29M
  short* ctxb = (short*)(wsb + (33u << 20));          // bf16 ctx(T) 8MB @33M
  short* ao = (short*)(wsb + (20u << 20));  // bf16 AO(T) 4MB (reuses wqb/wkvb)

  prep<<<2048, 256, 0, stream>>>(mask, pmws, Wq, Wkv, Wo, x, ctx,
                                 wqb, wkvb, wob, xb, ctxb);
  qkv_gemm<<<640, 256, 0, stream>>>(xb, ctxb, wqb, wkvb, bkv, qws, kws, vtws);
  attn_split<<<512, 512, 0, stream>>>(qws, kws, vtws, (const unsigned int*)pmws,
                                      opart, lpart);
  combine<<<2048, 256, 0, stream>>>(opart, lpart, ao);
  o_gemm<<<512, 256, 0, stream>>>(ao, wob, out);
}